// Round 1
// baseline (1397.976 us; speedup 1.0000x reference)
//
#include <hip/hip_runtime.h>
#include <hip/hip_bf16.h>

#define BB 32
#define DIM 4096
#define NH 32
#define NKV 8
#define HD 128
#define KVLEN 4096
#define QKVC 6144  // DIM + 2*NKV*HD
#define GQ 4

// ---------------- kernel A: xqkv = x @ wqkv (K-split + atomics) ----------------
__global__ __launch_bounds__(256) void k_qkv(const float* __restrict__ x,
                                             const float* __restrict__ w,
                                             float* __restrict__ xqkv) {
    int j  = blockIdx.x * 256 + threadIdx.x;   // column 0..6143 (24 blocks)
    int d0 = blockIdx.y * 256;                 // K-split (16 splits)
    float acc[BB];
#pragma unroll
    for (int b = 0; b < BB; ++b) acc[b] = 0.f;
    for (int dd = d0; dd < d0 + 256; dd += 4) {
        float w0 = w[(size_t)(dd + 0) * QKVC + j];
        float w1 = w[(size_t)(dd + 1) * QKVC + j];
        float w2 = w[(size_t)(dd + 2) * QKVC + j];
        float w3 = w[(size_t)(dd + 3) * QKVC + j];
#pragma unroll
        for (int b = 0; b < BB; ++b) {
            float4 xv = *(const float4*)&x[b * DIM + dd];  // wave-uniform broadcast
            acc[b] = fmaf(xv.x, w0, fmaf(xv.y, w1, fmaf(xv.z, w2, fmaf(xv.w, w3, acc[b]))));
        }
    }
#pragma unroll
    for (int b = 0; b < BB; ++b) atomicAdd(&xqkv[(size_t)b * QKVC + j], acc[b]);
}

// ---------------- kernel R: rotary for q,k; cache update; v passthrough --------
__global__ __launch_bounds__(128) void k_rot(const float* __restrict__ xqkv,
                                             const float* __restrict__ rot,
                                             const int* __restrict__ curpos,
                                             float* __restrict__ qws,
                                             float* __restrict__ ck,
                                             float* __restrict__ cv) {
    int c  = blockIdx.x;    // 0..47: 0-31 q heads, 32-39 k heads, 40-47 v heads
    int b  = blockIdx.y;    // batch
    int dp = threadIdx.x;   // 0..127 output dim
    int pos = *curpos;
    const float* row = &xqkv[(size_t)b * QKVC + c * HD];  // row base = c*128 for all c
    if (c < 40) {
        float acc = 0.f;
#pragma unroll 4
        for (int d = 0; d < HD; ++d) acc = fmaf(row[d], rot[d * HD + dp], acc);
        if (c < 32) {
            qws[((size_t)b * NH + c) * HD + dp] = acc;
        } else {
            int kvh = c - 32;
            ck[(((size_t)b * NKV + kvh) * KVLEN + pos) * HD + dp] = acc;
        }
    } else {
        int kvh = c - 40;
        cv[(((size_t)b * NKV + kvh) * KVLEN + pos) * HD + dp] = row[dp];
    }
}

// ---------------- kernel B1: scores = QK^T*scale + mask, online (m,l) ----------
__global__ __launch_bounds__(256) void k_qk(const float* __restrict__ ck,
                                            const float* __restrict__ qws,
                                            const float* __restrict__ mask,
                                            const int* __restrict__ curpos,
                                            float* __restrict__ scores,
                                            float2* __restrict__ stats) {
    __shared__ float Kl[64 * 132];   // 64 keys x 128 dims, stride 132 (pad)
    __shared__ float ql[4 * 128];    // 4 heads of q
    int bkv = blockIdx.x;            // 0..255
    int split = blockIdx.y;          // 0..3 (1024 keys each)
    int b = bkv >> 3, kv = bkv & 7;
    int tid = threadIdx.x;
    int g = tid >> 6, lane = tid & 63;   // wave = head
    int pos = *curpos;
    int L = min((((pos + 1) + 31) >> 5) << 5, KVLEN);

    for (int i = tid; i < GQ * HD; i += 256)
        ql[i] = qws[((size_t)b * NH + kv * GQ) * HD + i];
    __syncthreads();

    const float scale = 0.08838834764831845f;  // 1/sqrt(128)
    float m = -3.0e38f, lsum = 0.f;
    int l0 = split * 1024;
    int h = kv * GQ + g;

    for (int t = 0; t < 16; ++t) {
        const float4* Kg = (const float4*)&ck[((size_t)bkv * KVLEN + l0 + t * 64) * HD];
#pragma unroll
        for (int i = 0; i < 8; ++i) {
            int c4i = i * 256 + tid;
            int row = c4i >> 5, c4 = c4i & 31;
            *(float4*)&Kl[row * 132 + c4 * 4] = Kg[row * 32 + c4];
        }
        __syncthreads();
        float s = 0.f;
#pragma unroll
        for (int d4 = 0; d4 < 32; ++d4) {
            float4 kk = *(const float4*)&Kl[lane * 132 + d4 * 4];
            float4 qq = *(const float4*)&ql[g * HD + d4 * 4];
            s += kk.x * qq.x + kk.y * qq.y + kk.z * qq.z + kk.w * qq.w;
        }
        int l = l0 + t * 64 + lane;
        s = s * scale + mask[((size_t)h * BB + b) * KVLEN + l];
        if (l >= L) {
            s = -3.0e38f;
        } else {
            if (s > m) { lsum = lsum * __expf(m - s) + 1.f; m = s; }
            else       { lsum += __expf(s - m); }
        }
        scores[((size_t)(bkv * GQ + g)) * KVLEN + l] = s;
        __syncthreads();
    }
    // wave reduce (m, lsum) over 64 lanes
#pragma unroll
    for (int off = 32; off > 0; off >>= 1) {
        float mo = __shfl_xor(m, off);
        float lo = __shfl_xor(lsum, off);
        float M2 = fmaxf(m, mo);
        lsum = lsum * __expf(m - M2) + lo * __expf(mo - M2);
        m = M2;
    }
    if (lane == 0) stats[(bkv * GQ + g) * 4 + split] = make_float2(m, lsum);
}

// ---------------- kernel S: merge split stats -> (M, 1/L) ----------------------
__global__ void k_stats(const float2* __restrict__ stats, float2* __restrict__ mfin) {
    int i = blockIdx.x * 256 + threadIdx.x;  // 0..1023 = (bkv*4+g)
    if (i >= BB * NKV * GQ) return;
    float m = -3.0e38f, l = 0.f;
#pragma unroll
    for (int s = 0; s < 4; ++s) {
        float2 p = stats[i * 4 + s];
        float M2 = fmaxf(m, p.x);
        l = l * __expf(m - M2) + p.y * __expf(p.x - M2);
        m = M2;
    }
    mfin[i] = make_float2(m, l > 0.f ? 1.f / l : 0.f);
}

// ---------------- kernel B2: out = P @ V ---------------------------------------
__global__ __launch_bounds__(512) void k_pv(const float* __restrict__ cv,
                                            const float* __restrict__ scores,
                                            const float2* __restrict__ mfin,
                                            float* __restrict__ attn) {
    __shared__ float p_lds[4][GQ][512];   // [sub][g][l] 32 KB
    __shared__ float o_lds[4][GQ][HD];    // 8 KB
    int bkv = blockIdx.x;
    int tid = threadIdx.x;
    int sub = tid >> 7, d = tid & 127;
    float acc[GQ] = {0.f, 0.f, 0.f, 0.f};
    float2 ML[GQ];
#pragma unroll
    for (int g = 0; g < GQ; ++g) ML[g] = mfin[bkv * GQ + g];

    for (int half = 0; half < 2; ++half) {
        int l0 = sub * 1024 + half * 512;
        // compute probabilities for this chunk
#pragma unroll
        for (int i = 0; i < 16; ++i) {
            int flat = i * 128 + (tid & 127);  // 0..2047
            int g = flat >> 9, l = flat & 511;
            float s = scores[((size_t)(bkv * GQ + g)) * KVLEN + l0 + l];
            p_lds[sub][g][l] = __expf(s - ML[g].x) * ML[g].y;
        }
        __syncthreads();
        const float* Vg = &cv[((size_t)bkv * KVLEN + l0) * HD];
#pragma unroll 4
        for (int l = 0; l < 512; ++l) {
            float v = Vg[(size_t)l * HD + d];
#pragma unroll
            for (int g = 0; g < GQ; ++g) acc[g] = fmaf(p_lds[sub][g][l], v, acc[g]);
        }
        __syncthreads();
    }
#pragma unroll
    for (int g = 0; g < GQ; ++g) o_lds[sub][g][d] = acc[g];
    __syncthreads();
    {   // 512 threads reduce 4 subs for (g,d)
        int g = tid >> 7, d2 = tid & 127;
        float o = o_lds[0][g][d2] + o_lds[1][g][d2] + o_lds[2][g][d2] + o_lds[3][g][d2];
        int b = bkv >> 3, kv = bkv & 7;
        attn[(size_t)b * DIM + (kv * GQ + g) * HD + d2] = o;
    }
}

// ---------------- kernel C: out = attn @ wo (K-split + atomics) ----------------
__global__ __launch_bounds__(256) void k_wo(const float* __restrict__ attn,
                                            const float* __restrict__ wo,
                                            float* __restrict__ out) {
    int j  = blockIdx.x * 256 + threadIdx.x;   // 0..4095 (16 blocks)
    int d0 = blockIdx.y * 256;                 // 16 splits
    float acc[BB];
#pragma unroll
    for (int b = 0; b < BB; ++b) acc[b] = 0.f;
    for (int dd = d0; dd < d0 + 256; dd += 4) {
        float w0 = wo[(size_t)(dd + 0) * DIM + j];
        float w1 = wo[(size_t)(dd + 1) * DIM + j];
        float w2 = wo[(size_t)(dd + 2) * DIM + j];
        float w3 = wo[(size_t)(dd + 3) * DIM + j];
#pragma unroll
        for (int b = 0; b < BB; ++b) {
            float4 av = *(const float4*)&attn[b * DIM + dd];  // uniform broadcast
            acc[b] = fmaf(av.x, w0, fmaf(av.y, w1, fmaf(av.z, w2, fmaf(av.w, w3, acc[b]))));
        }
    }
#pragma unroll
    for (int b = 0; b < BB; ++b) atomicAdd(&out[(size_t)b * DIM + j], acc[b]);
}

extern "C" void kernel_launch(void* const* d_in, const int* in_sizes, int n_in,
                              void* d_out, int out_size, void* d_ws, size_t ws_size,
                              hipStream_t stream) {
    const float* x    = (const float*)d_in[0];
    const float* wqkv = (const float*)d_in[1];
    const float* wo   = (const float*)d_in[2];
    const float* rot  = (const float*)d_in[3];
    float* ck         = (float*)d_in[4];   // mutated: row current_pos (restored by harness)
    float* cv         = (float*)d_in[5];
    const float* mask = (const float*)d_in[6];
    const int* curpos = (const int*)d_in[7];
    float* out        = (float*)d_out;

    char* ws = (char*)d_ws;
    float*  xqkv   = (float*)(ws);                      // 32*6144*4      = 786432
    float*  qws    = (float*)(ws + 786432);             // 32*32*128*4    = 524288
    float*  scores = (float*)(ws + 1310720);            // 1024*4096*4    = 16777216
    float2* stats  = (float2*)(ws + 18087936);          // 1024*4*8       = 32768
    float2* mfin   = (float2*)(ws + 18120704);          // 1024*8         = 8192
    float*  attn   = (float*)(ws + 18128896);           // 32*4096*4      = 524288
    // total ws used ~18.7 MB

    hipMemsetAsync(xqkv, 0, 786432, stream);
    hipMemsetAsync(out, 0, (size_t)out_size * sizeof(float), stream);

    k_qkv <<<dim3(QKVC / 256, 16), 256, 0, stream>>>(x, wqkv, xqkv);
    k_rot <<<dim3(48, BB),        128, 0, stream>>>(xqkv, rot, curpos, qws, ck, cv);
    k_qk  <<<dim3(BB * NKV, 4),   256, 0, stream>>>(ck, qws, mask, curpos, scores, stats);
    k_stats<<<dim3(4),            256, 0, stream>>>(stats, mfin);
    k_pv  <<<dim3(BB * NKV),      512, 0, stream>>>(cv, scores, mfin, attn);
    k_wo  <<<dim3(DIM / 256, 16), 256, 0, stream>>>(attn, wo, out);
}